// Round 1
// baseline (180.933 us; speedup 1.0000x reference)
//
#include <hip/hip_runtime.h>

#define B_    2048
#define S_    512
#define DE_   50
#define DIN_  100
#define H_    512
#define OUT_  2

// ---------------- Kernel 1: embedding gather + masked mean pooling ----------
// One block per batch row. 4 waves; each wave walks tokens s = wave, wave+4,...
// Lanes 0..49 hold one embedding dim each (coalesced 200B row read).
__global__ __launch_bounds__(256) void pool_kernel(
    const float* __restrict__ emb, const float* __restrict__ post,
    const int* __restrict__ seq, const int* __restrict__ seqlen,
    const int* __restrict__ pos, float* __restrict__ pooled)
{
    const int b    = blockIdx.x;
    const int L    = seqlen[b];
    const int lane = threadIdx.x & 63;
    const int wave = threadIdx.x >> 6;

    const int* seqrow = seq + (size_t)b * S_;
    const int* posrow = pos + (size_t)b * S_;

    float accE = 0.f, accP = 0.f;
    for (int s = wave; s < L; s += 4) {
        // s is wave-uniform -> scalar loads
        int tok = __builtin_amdgcn_readfirstlane(seqrow[s]);
        int p   = __builtin_amdgcn_readfirstlane(posrow[s]);
        if (lane < DE_) {
            accE += emb [(size_t)tok * DE_ + lane];
            accP += post[(size_t)p   * DE_ + lane];
        }
    }

    __shared__ float red[4][DIN_];
    if (lane < DE_) {
        red[wave][lane]       = accE;
        red[wave][lane + DE_] = accP;
    }
    __syncthreads();

    if (threadIdx.x < DIN_) {
        float s = red[0][threadIdx.x] + red[1][threadIdx.x] +
                  red[2][threadIdx.x] + red[3][threadIdx.x];
        pooled[(size_t)b * DIN_ + threadIdx.x] = s / (float)L;
    }
}

// ---------------- Kernel 2: fused 4-layer MLP --------------------------------
// 256 blocks x 256 threads; each block owns 8 batch rows, h stays in LDS.
// Each thread computes cols {tid, tid+256} for all 8 rows (16 acc chains).
template<int K>
__device__ __forceinline__ void dense_relu_256(
    const float (&hin)[8][K], float (&hout)[8][H_],
    const float* __restrict__ W, const float* __restrict__ bias, int tid)
{
    const int c0 = tid, c1 = tid + 256;
    float acc0[8], acc1[8];
#pragma unroll
    for (int r = 0; r < 8; ++r) { acc0[r] = 0.f; acc1[r] = 0.f; }

    for (int k = 0; k < K; k += 4) {
        float a[8][4];
#pragma unroll
        for (int r = 0; r < 8; ++r) {
            float4 v = *(const float4*)&hin[r][k];   // LDS broadcast read
            a[r][0] = v.x; a[r][1] = v.y; a[r][2] = v.z; a[r][3] = v.w;
        }
#pragma unroll
        for (int kk = 0; kk < 4; ++kk) {
            float w0 = W[(size_t)(k + kk) * H_ + c0];
            float w1 = W[(size_t)(k + kk) * H_ + c1];
#pragma unroll
            for (int r = 0; r < 8; ++r) {
                acc0[r] = fmaf(a[r][kk], w0, acc0[r]);
                acc1[r] = fmaf(a[r][kk], w1, acc1[r]);
            }
        }
    }
    float bb0 = bias[c0], bb1 = bias[c1];
#pragma unroll
    for (int r = 0; r < 8; ++r) {
        hout[r][c0] = fmaxf(acc0[r] + bb0, 0.f);
        hout[r][c1] = fmaxf(acc1[r] + bb1, 0.f);
    }
}

__global__ __launch_bounds__(256) void mlp_kernel(
    const float* __restrict__ pooled,
    const float* __restrict__ W1, const float* __restrict__ b1,
    const float* __restrict__ W2, const float* __restrict__ b2,
    const float* __restrict__ W3, const float* __restrict__ b3,
    const float* __restrict__ Wf, const float* __restrict__ bf,
    float* __restrict__ out)
{
    __shared__ float p_s[8][DIN_];
    __shared__ float hA[8][H_];
    __shared__ float hB[8][H_];

    const int tid = threadIdx.x;
    const int b0  = blockIdx.x * 8;

    for (int i = tid; i < 8 * DIN_; i += 256)
        ((float*)p_s)[i] = pooled[(size_t)b0 * DIN_ + i];
    __syncthreads();

    dense_relu_256<DIN_>(p_s, hA, W1, b1, tid);
    __syncthreads();
    dense_relu_256<H_>(hA, hB, W2, b2, tid);
    __syncthreads();
    dense_relu_256<H_>(hB, hA, W3, b3, tid);
    __syncthreads();

    // final: [8,512] @ [512,2] -> 16 outputs, one per (wave, iteration)
    const int wave = tid >> 6, lane = tid & 63;
    for (int oi = wave; oi < 8 * OUT_; oi += 4) {
        const int r = oi >> 1, o = oi & 1;
        float psum = 0.f;
        for (int k = lane; k < H_; k += 64)
            psum = fmaf(hA[r][k], Wf[(size_t)k * OUT_ + o], psum);
#pragma unroll
        for (int off = 32; off; off >>= 1)
            psum += __shfl_down(psum, off);
        if (lane == 0) out[(size_t)(b0 + r) * OUT_ + o] = psum + bf[o];
    }
}

extern "C" void kernel_launch(void* const* d_in, const int* in_sizes, int n_in,
                              void* d_out, int out_size, void* d_ws, size_t ws_size,
                              hipStream_t stream)
{
    const float* emb    = (const float*)d_in[0];
    const float* post   = (const float*)d_in[1];
    const float* W1     = (const float*)d_in[2];
    const float* b1     = (const float*)d_in[3];
    const float* W2     = (const float*)d_in[4];
    const float* b2     = (const float*)d_in[5];
    const float* W3     = (const float*)d_in[6];
    const float* b3     = (const float*)d_in[7];
    const float* Wf     = (const float*)d_in[8];
    const float* bf     = (const float*)d_in[9];
    const int*   seq    = (const int*)d_in[10];
    const int*   seqlen = (const int*)d_in[11];
    const int*   pos    = (const int*)d_in[12];
    float*       out    = (float*)d_out;

    float* pooled = (float*)d_ws;   // 2048*100 floats = 800 KB scratch

    pool_kernel<<<B_, 256, 0, stream>>>(emb, post, seq, seqlen, pos, pooled);
    mlp_kernel<<<B_ / 8, 256, 0, stream>>>(pooled, W1, b1, W2, b2, W3, b3,
                                           Wf, bf, out);
}

// Round 2
// 94.806 us; speedup vs baseline: 1.9085x; 1.9085x over previous
//
#include <hip/hip_runtime.h>

typedef __attribute__((ext_vector_type(8))) short bf16x8;
typedef __attribute__((ext_vector_type(4))) float f32x4;

#define B_    2048
#define S_    512

// ws layout (bytes). Total 1.64 MB.
#define OFF_POOLED 0u          // 2048*128*2 = 524288   pooled bf16, K padded 100->128
#define OFF_WT1    524288u     // 512*128*2  = 131072   Wt1[n][k] (transposed, k<100 real)
#define OFF_WT2    655360u     // 512*512*2  = 524288   Wt2[n][k]
#define OFF_WT3    1179648u    // 512*512*2  = 524288   Wt3[n][k]
#define OFF_WTF    1703936u    // 16*512*2   = 16384    Wtf[n][k], n<2 real

__device__ __forceinline__ unsigned short f2bf(float f) {
    unsigned int u = __float_as_uint(f);
    u += 0x7FFFu + ((u >> 16) & 1u);          // round-to-nearest-even
    return (unsigned short)(u >> 16);
}

#define MFMA16(a, b, c) __builtin_amdgcn_mfma_f32_16x16x32_bf16((a), (b), (c), 0, 0, 0)

// ---------------- convert: fp32 weights -> transposed/padded bf16 in ws ------
__global__ __launch_bounds__(256) void convert_kernel(
    const float* __restrict__ W1, const float* __restrict__ W2,
    const float* __restrict__ W3, const float* __restrict__ Wf,
    unsigned short* __restrict__ ws)
{
    unsigned short* Wt1 = ws + OFF_WT1 / 2;
    unsigned short* Wt2 = ws + OFF_WT2 / 2;
    unsigned short* Wt3 = ws + OFF_WT3 / 2;
    unsigned short* Wtf = ws + OFF_WTF / 2;
    int i = blockIdx.x * 256 + threadIdx.x;
    if (i < 65536) {                                   // Wt1[n][k], k in [0,128)
        int n = i >> 7, k = i & 127;
        Wt1[i] = f2bf(k < 100 ? W1[k * 512 + n] : 0.f);
    } else if (i < 65536 + 262144) {                   // Wt2[n][k]
        int j = i - 65536; int n = j >> 9, k = j & 511;
        Wt2[j] = f2bf(W2[k * 512 + n]);
    } else if (i < 65536 + 524288) {                   // Wt3[n][k]
        int j = i - (65536 + 262144); int n = j >> 9, k = j & 511;
        Wt3[j] = f2bf(W3[k * 512 + n]);
    } else {                                           // Wtf[n][k], n<2 real
        int j = i - (65536 + 524288); int n = j >> 9, k = j & 511;
        Wtf[j] = f2bf(n < 2 ? Wf[k * 2 + n] : 0.f);
    }
}

// ---------------- pool: gather + masked mean, writes bf16 [2048][128] --------
__global__ __launch_bounds__(256) void pool_kernel(
    const float* __restrict__ emb, const float* __restrict__ post,
    const int* __restrict__ seq, const int* __restrict__ seqlen,
    const int* __restrict__ pos, unsigned short* __restrict__ pooled_p)
{
    const int b    = blockIdx.x;
    const int L    = seqlen[b];
    const int tid  = threadIdx.x;
    const int lane = tid & 63;
    const int wave = tid >> 6;
    const int* seqrow = seq + (size_t)b * S_;
    const int* posrow = pos + (size_t)b * S_;

    float aE[4] = {0.f, 0.f, 0.f, 0.f};
    float aP[4] = {0.f, 0.f, 0.f, 0.f};

    for (int c0 = 0; c0 < L; c0 += 64) {
        // wave w owns tokens c0 + w*16 .. +15; indices fetched coalesced into lanes 0..15
        int myi = c0 + wave * 16 + (lane & 15);
        int sv = 0, pv = 0;
        if ((lane < 16) && (myi < L)) { sv = seqrow[myi]; pv = posrow[myi]; }
#pragma unroll
        for (int j = 0; j < 16; ++j) {
            int tok = __shfl(sv, j);
            int p   = __shfl(pv, j);
            bool valid = (c0 + wave * 16 + j) < L;     // wave-uniform
            if (valid && lane < 50) {
                aE[j & 3] += emb [(size_t)tok * 50 + lane];
                aP[j & 3] += post[(size_t)p   * 50 + lane];
            }
        }
    }
    float accE = (aE[0] + aE[1]) + (aE[2] + aE[3]);
    float accP = (aP[0] + aP[1]) + (aP[2] + aP[3]);

    __shared__ float red[4][100];
    if (lane < 50) { red[wave][lane] = accE; red[wave][lane + 50] = accP; }
    __syncthreads();
    if (tid < 128) {
        float v = 0.f;
        if (tid < 100)
            v = (red[0][tid] + red[1][tid] + red[2][tid] + red[3][tid]) / (float)L;
        pooled_p[(size_t)b * 128 + tid] = f2bf(v);
    }
}

// ---------------- fused bf16-MFMA MLP ----------------------------------------
// Block: 8 real rows (M padded to 16), 512 threads = 8 waves x 64-col panel.
// Activations ping-pong in swizzled LDS (16 rows x 512 cols bf16 = 16 KB each).

__device__ __forceinline__ void load_afrags(bf16x8 (&a)[16],
    const unsigned short* h, int row, int kq)
{
#pragma unroll
    for (int ks = 0; ks < 16; ++ks)
        a[ks] = *(const bf16x8*)((const char*)h +
                  (((unsigned)(row * 1024 + ks * 64 + kq * 16)) ^ ((row & 7) << 4)));
}

template<int KS>
__device__ __forceinline__ void layer_compute(
    const bf16x8 (&a)[KS], const unsigned short* __restrict__ Wt,
    const float* __restrict__ bias, unsigned short* hout,
    int wave, int row, int kq)
{
#pragma unroll
    for (int nt = 0; nt < 4; nt += 2) {
        const int c0 = wave * 64 + nt * 16 + row;
        const int c1 = c0 + 16;
        f32x4 acc0 = {0.f, 0.f, 0.f, 0.f};
        f32x4 acc1 = {0.f, 0.f, 0.f, 0.f};
        const unsigned short* p0 = Wt + (size_t)c0 * (KS * 32) + kq * 8;
        const unsigned short* p1 = Wt + (size_t)c1 * (KS * 32) + kq * 8;
#pragma unroll
        for (int ks = 0; ks < KS; ++ks) {
            bf16x8 bv0 = *(const bf16x8*)(p0 + ks * 32);
            bf16x8 bv1 = *(const bf16x8*)(p1 + ks * 32);
            acc0 = MFMA16(a[ks], bv0, acc0);
            acc1 = MFMA16(a[ks], bv1, acc1);
        }
        const float bb0 = bias[c0], bb1 = bias[c1];
#pragma unroll
        for (int r = 0; r < 4; ++r) {
            int hrow = kq * 4 + r;
            unsigned base = hrow * 1024;
            *(unsigned short*)((char*)hout + ((base + c0 * 2) ^ ((hrow & 7) << 4))) =
                f2bf(fmaxf(acc0[r] + bb0, 0.f));
            *(unsigned short*)((char*)hout + ((base + c1 * 2) ^ ((hrow & 7) << 4))) =
                f2bf(fmaxf(acc1[r] + bb1, 0.f));
        }
    }
}

__global__ __launch_bounds__(512) void mlp_kernel(
    const unsigned short* __restrict__ ws_ro,
    const float* __restrict__ b1, const float* __restrict__ b2,
    const float* __restrict__ b3, const float* __restrict__ bfin,
    float* __restrict__ out)
{
    __shared__ unsigned short hA[8192];
    __shared__ unsigned short hB[8192];

    const int tid  = threadIdx.x;
    const int wave = tid >> 6;
    const int lane = tid & 63;
    const int row  = lane & 15;   // M-row (A/D) and N-col (B)
    const int kq   = lane >> 4;   // k-quarter
    const int b0   = blockIdx.x * 8;

    const unsigned short* pooled = ws_ro + OFF_POOLED / 2;
    const unsigned short* Wt1    = ws_ro + OFF_WT1 / 2;
    const unsigned short* Wt2    = ws_ro + OFF_WT2 / 2;
    const unsigned short* Wt3    = ws_ro + OFF_WT3 / 2;
    const unsigned short* Wtf    = ws_ro + OFF_WTF / 2;

    // ---- Layer 1 (K=128, A straight from global; rows 8..15 are pad/garbage)
    bf16x8 a1[4];
#pragma unroll
    for (int ks = 0; ks < 4; ++ks)
        a1[ks] = *(const bf16x8*)(pooled + (size_t)(b0 + row) * 128 + ks * 32 + kq * 8);
    layer_compute<4>(a1, Wt1, b1, hA, wave, row, kq);
    __syncthreads();

    // ---- Layer 2 (K=512): hA -> hB
    bf16x8 a[16];
    load_afrags(a, hA, row, kq);
    layer_compute<16>(a, Wt2, b2, hB, wave, row, kq);
    __syncthreads();

    // ---- Layer 3 (K=512): hB -> hA
    load_afrags(a, hB, row, kq);
    layer_compute<16>(a, Wt3, b3, hA, wave, row, kq);
    __syncthreads();

    // ---- Final (K=512, N padded 2->16): wave 0 only
    if (wave == 0) {
        load_afrags(a, hA, row, kq);
        f32x4 acc = {0.f, 0.f, 0.f, 0.f};
        const unsigned short* pw = Wtf + (size_t)row * 512 + kq * 8;
#pragma unroll
        for (int ks = 0; ks < 16; ++ks) {
            bf16x8 bv = *(const bf16x8*)(pw + ks * 32);
            acc = MFMA16(a[ks], bv, acc);
        }
        if (row < 2 && kq < 2) {
            float bb = bfin[row];
#pragma unroll
            for (int r = 0; r < 4; ++r) {
                int m = kq * 4 + r;                      // real rows 0..7
                out[(size_t)(b0 + m) * 2 + row] = acc[r] + bb;
            }
        }
    }
}

extern "C" void kernel_launch(void* const* d_in, const int* in_sizes, int n_in,
                              void* d_out, int out_size, void* d_ws, size_t ws_size,
                              hipStream_t stream)
{
    const float* emb    = (const float*)d_in[0];
    const float* post   = (const float*)d_in[1];
    const float* W1     = (const float*)d_in[2];
    const float* b1     = (const float*)d_in[3];
    const float* W2     = (const float*)d_in[4];
    const float* b2     = (const float*)d_in[5];
    const float* W3     = (const float*)d_in[6];
    const float* b3     = (const float*)d_in[7];
    const float* Wf     = (const float*)d_in[8];
    const float* bf     = (const float*)d_in[9];
    const int*   seq    = (const int*)d_in[10];
    const int*   seqlen = (const int*)d_in[11];
    const int*   pos    = (const int*)d_in[12];
    float*       out    = (float*)d_out;

    unsigned short* ws = (unsigned short*)d_ws;

    convert_kernel<<<2336, 256, 0, stream>>>(W1, W2, W3, Wf, ws);
    pool_kernel<<<B_, 256, 0, stream>>>(emb, post, seq, seqlen, pos,
                                        ws + OFF_POOLED / 2);
    mlp_kernel<<<B_ / 8, 512, 0, stream>>>(ws, b1, b2, b3, bf, out);
}